// Round 1
// baseline (191.393 us; speedup 1.0000x reference)
//
#include <hip/hip_runtime.h>

#define T_TOTAL 200000
#define NL 49
#define NP 50
#define NB 20
#define TB 32           // timesteps per block
#define THREADS 256

// ---------------------------------------------------------------------------
// Fused kernel: per block stages TB+1 timesteps (halo for temporal diff),
// computes limb deltas, tree-accumulates to the 50 node positions, writes
// x,y,z, and accumulates loss and reg2 partials.
// ---------------------------------------------------------------------------
__global__ __launch_bounds__(THREADS) void bbf_fused(
    const float* __restrict__ lines,
    const float* __restrict__ rootsx,
    const float* __restrict__ rootsy,
    const float* __restrict__ rootsz,
    const float* __restrict__ ax,
    const float* __restrict__ ay,
    const float* __restrict__ az,
    const float* __restrict__ tarx,
    const float* __restrict__ tary,
    const float* __restrict__ w,
    float* __restrict__ outx,
    float* __restrict__ outy,
    float* __restrict__ outz,
    double* __restrict__ accum)   // accum[0]=loss numerator, accum[1]=reg2 numerator
{
    __shared__ float sdx[(TB + 1) * NL];
    __shared__ float sdy[(TB + 1) * NL];
    __shared__ float sdz[(TB + 1) * NL];
    __shared__ float xs[(TB + 1) * NP];
    __shared__ float ys[(TB + 1) * NP];
    __shared__ float zs[(TB + 1) * NP];
    __shared__ float Lexp[NB];
    __shared__ double redL[THREADS / 64], redR[THREADS / 64];

    const int tid = threadIdx.x;
    const int t0  = blockIdx.x * TB;
    const int nT  = min(TB + 1, T_TOTAL - t0);   // staged timesteps incl. halo
    const int nload = nT * NL;

    if (tid < NB) Lexp[tid] = expf(lines[tid]);

    // Phase 1: coalesced global -> LDS copy of angles
    for (int k = tid; k < nload; k += THREADS) {
        const int gk = t0 * NL + k;
        sdx[k] = ax[gk];
        sdy[k] = ay[gk];
        sdz[k] = az[gk];
    }
    __syncthreads();

    // Phase 2: deltas in place: d = exp(lines[bone]) * a / (|a|+eps)
    for (int k = tid; k < nload; k += THREADS) {
        const int i = k % NL;               // limb index
        const float x = sdx[k], y = sdy[k], z = sdz[k];
        const float nrm = sqrtf(x * x + y * y + z * z) + 1e-10f;
        const float s = Lexp[i % NB] / nrm;
        sdx[k] = x * s;
        sdy[k] = y * s;
        sdz[k] = z * s;
    }
    __syncthreads();

    // Phase 3: tree accumulation -> node positions in LDS
    const int npts = nT * NP;
    for (int j = tid; j < npts; j += THREADS) {
        const int t = j / NP;
        const int p = j - t * NP;
        float X = 0.f, Y = 0.f, Z = 0.f;
        int b = p;
        while (b > 0) {                     // <=5 iterations (tree depth)
            const int limb = b - 1;
            const int idx = t * NL + limb;
            X += sdx[idx];
            Y += sdy[idx];
            Z += sdz[idx];
            b = limb >> 1;                  // parent = (b-1)/2
        }
        const int tg = t0 + t;
        xs[j] = X + rootsx[tg];
        ys[j] = Y + rootsy[tg];
        zs[j] = Z + rootsz[tg];
    }
    __syncthreads();

    // Phase 4: write outputs, accumulate loss + reg2 partials
    float lossAcc = 0.f, regAcc = 0.f;
    for (int j = tid; j < TB * NP; j += THREADS) {
        const int g = t0 * NP + j;
        const float X = xs[j], Y = ys[j], Z = zs[j];
        outx[g] = X;
        outy[g] = Y;
        outz[g] = Z;
        const float wv = w[g];
        const float dx = X - tarx[g];
        const float dy = Y - tary[g];
        lossAcc += wv * (dx * dx + dy * dy);
        const int t = t0 + j / NP;
        if (t < T_TOTAL - 1) {
            const float ddx = X - xs[j + NP];
            const float ddy = Y - ys[j + NP];
            const float ddz = Z - zs[j + NP];
            regAcc += ddx * ddx + ddy * ddy + ddz * ddz;
        }
    }

    // Block reduction (wave shuffle, then cross-wave via LDS), double atomics
    for (int off = 32; off > 0; off >>= 1) {
        lossAcc += __shfl_down(lossAcc, off);
        regAcc  += __shfl_down(regAcc, off);
    }
    const int wid = tid >> 6;
    if ((tid & 63) == 0) { redL[wid] = (double)lossAcc; redR[wid] = (double)regAcc; }
    __syncthreads();
    if (tid == 0) {
        double l = 0.0, r = 0.0;
        for (int i = 0; i < THREADS / 64; ++i) { l += redL[i]; r += redR[i]; }
        atomicAdd(&accum[0], l);
        atomicAdd(&accum[1], r);
    }
}

__global__ void bbf_finalize(const float* __restrict__ lines,
                             const double* __restrict__ accum,
                             float* __restrict__ out_total)
{
    if (threadIdx.x == 0 && blockIdx.x == 0) {
        double reg1 = 0.0;
        for (int i = 0; i < NB; ++i) reg1 += (double)expf(lines[i]);
        const double loss = accum[0] / ((double)T_TOTAL * (double)NP);
        const double reg2 = accum[1] / ((double)(T_TOTAL - 1) * (double)NP);
        *out_total = (float)(loss + 0.001 * reg1 + 0.1 * reg2);
    }
}

extern "C" void kernel_launch(void* const* d_in, const int* in_sizes, int n_in,
                              void* d_out, int out_size, void* d_ws, size_t ws_size,
                              hipStream_t stream) {
    const float* lines  = (const float*)d_in[0];
    const float* rootsx = (const float*)d_in[1];
    const float* rootsy = (const float*)d_in[2];
    const float* rootsz = (const float*)d_in[3];
    const float* ax     = (const float*)d_in[4];
    const float* ay     = (const float*)d_in[5];
    const float* az     = (const float*)d_in[6];
    const float* tarx   = (const float*)d_in[7];
    const float* tary   = (const float*)d_in[8];
    const float* w      = (const float*)d_in[9];

    float* out = (float*)d_out;
    const size_t plane = (size_t)T_TOTAL * NP;
    float* outx = out;
    float* outy = out + plane;
    float* outz = out + 2 * plane;
    float* out_total = out + 3 * plane;

    double* accum = (double*)d_ws;
    hipMemsetAsync(d_ws, 0, 2 * sizeof(double), stream);

    const int nblocks = (T_TOTAL + TB - 1) / TB;   // 6250
    bbf_fused<<<nblocks, THREADS, 0, stream>>>(
        lines, rootsx, rootsy, rootsz, ax, ay, az, tarx, tary, w,
        outx, outy, outz, accum);
    bbf_finalize<<<1, 64, 0, stream>>>(lines, accum, out_total);
}

// Round 2
// 105.824 us; speedup vs baseline: 1.8086x; 1.8086x over previous
//
#include <hip/hip_runtime.h>

#define T_TOTAL 200000
#define NL 49
#define NP 50
#define NB 20
#define TB 32           // timesteps per block (200000 % 32 == 0 -> 6250 full blocks)
#define THREADS 256
#define NBLK (T_TOTAL / TB)   // 6250

__global__ __launch_bounds__(THREADS) void bbf_fused(
    const float* __restrict__ lines,
    const float* __restrict__ rootsx,
    const float* __restrict__ rootsy,
    const float* __restrict__ rootsz,
    const float* __restrict__ ax,
    const float* __restrict__ ay,
    const float* __restrict__ az,
    const float* __restrict__ tarx,
    const float* __restrict__ tary,
    const float* __restrict__ w,
    float* __restrict__ outx,
    float* __restrict__ outy,
    float* __restrict__ outz,
    double* __restrict__ partials)   // [NBLK][2]: loss, reg2 per block
{
    __shared__ __align__(16) float sdx[(TB + 1) * NL];
    __shared__ __align__(16) float sdy[(TB + 1) * NL];
    __shared__ __align__(16) float sdz[(TB + 1) * NL];
    __shared__ __align__(16) float xs[(TB + 1) * NP];
    __shared__ __align__(16) float ys[(TB + 1) * NP];
    __shared__ __align__(16) float zs[(TB + 1) * NP];
    __shared__ float Lexp[NL];       // per-limb length (pre-expanded, kills %NB)
    __shared__ double redL[THREADS / 64], redR[THREADS / 64];

    const int tid = threadIdx.x;
    const int t0  = blockIdx.x * TB;
    const int nT  = min(TB + 1, T_TOTAL - t0);   // 33, last block 32
    const int nload = nT * NL;

    if (tid < NL) Lexp[tid] = expf(lines[tid % NB]);
    __syncthreads();

    // Phase 1+2 merged: float4 global loads -> deltas -> LDS
    // base offset t0*NL floats = blockIdx*1568 floats -> 16B aligned
    const float4* ax4 = (const float4*)(ax + (size_t)t0 * NL);
    const float4* ay4 = (const float4*)(ay + (size_t)t0 * NL);
    const float4* az4 = (const float4*)(az + (size_t)t0 * NL);
    const int nv4 = nload >> 2;
    for (int k4 = tid; k4 < nv4; k4 += THREADS) {
        const float4 X = ax4[k4];
        const float4 Y = ay4[k4];
        const float4 Z = az4[k4];
        const float fx[4] = {X.x, X.y, X.z, X.w};
        const float fy[4] = {Y.x, Y.y, Y.z, Y.w};
        const float fz[4] = {Z.x, Z.y, Z.z, Z.w};
        const int kb = k4 << 2;
#pragma unroll
        for (int c = 0; c < 4; ++c) {
            const int k = kb + c;
            const int i = k % NL;
            const float x = fx[c], y = fy[c], z = fz[c];
            const float nrm = sqrtf(x * x + y * y + z * z) + 1e-10f;
            const float s = Lexp[i] / nrm;
            sdx[k] = x * s;
            sdy[k] = y * s;
            sdz[k] = z * s;
        }
    }
    for (int k = (nv4 << 2) + tid; k < nload; k += THREADS) {   // tail (<=1617%4)
        const int i = k % NL;
        const float x = ax[(size_t)t0 * NL + k];
        const float y = ay[(size_t)t0 * NL + k];
        const float z = az[(size_t)t0 * NL + k];
        const float nrm = sqrtf(x * x + y * y + z * z) + 1e-10f;
        const float s = Lexp[i] / nrm;
        sdx[k] = x * s;
        sdy[k] = y * s;
        sdz[k] = z * s;
    }
    __syncthreads();

    // Phase 3: tree accumulation -> node positions in LDS
    const int npts = nT * NP;
    for (int j = tid; j < npts; j += THREADS) {
        const int t = j / NP;
        const int p = j - t * NP;
        float X = 0.f, Y = 0.f, Z = 0.f;
        int b = p;
        while (b > 0) {                     // <=5 iterations (tree depth)
            const int limb = b - 1;
            const int idx = t * NL + limb;
            X += sdx[idx];
            Y += sdy[idx];
            Z += sdz[idx];
            b = limb >> 1;                  // parent = (b-1)/2
        }
        const int tg = t0 + t;
        xs[j] = X + rootsx[tg];
        ys[j] = Y + rootsy[tg];
        zs[j] = Z + rootsz[tg];
    }
    __syncthreads();

    // Phase 4: float4 output writes + loss/reg2 partials
    const size_t gbase = (size_t)t0 * NP;   // blockIdx*1600 floats -> 16B aligned
    const float4* tarx4 = (const float4*)(tarx + gbase);
    const float4* tary4 = (const float4*)(tary + gbase);
    const float4* w4    = (const float4*)(w + gbase);
    float4* outx4 = (float4*)(outx + gbase);
    float4* outy4 = (float4*)(outy + gbase);
    float4* outz4 = (float4*)(outz + gbase);

    float lossAcc = 0.f, regAcc = 0.f;
    for (int c = tid; c < (TB * NP) / 4; c += THREADS) {   // 400 float4s
        const int j = c << 2;
        const float4 X  = *(const float4*)&xs[j];
        const float4 Y  = *(const float4*)&ys[j];
        const float4 Z  = *(const float4*)&zs[j];
        outx4[c] = X;
        outy4[c] = Y;
        outz4[c] = Z;
        const float4 TX = tarx4[c];
        const float4 TY = tary4[c];
        const float4 WV = w4[c];
        const float xv[4] = {X.x, X.y, X.z, X.w};
        const float yv[4] = {Y.x, Y.y, Y.z, Y.w};
        const float zv[4] = {Z.x, Z.y, Z.z, Z.w};
        const float tx[4] = {TX.x, TX.y, TX.z, TX.w};
        const float ty[4] = {TY.x, TY.y, TY.z, TY.w};
        const float wv[4] = {WV.x, WV.y, WV.z, WV.w};
#pragma unroll
        for (int e = 0; e < 4; ++e) {
            const int je = j + e;
            const float dx = xv[e] - tx[e];
            const float dy = yv[e] - ty[e];
            lossAcc += wv[e] * (dx * dx + dy * dy);
            const int t = t0 + je / NP;
            if (t < T_TOTAL - 1) {
                const float ddx = xv[e] - xs[je + NP];
                const float ddy = yv[e] - ys[je + NP];
                const float ddz = zv[e] - zs[je + NP];
                regAcc += ddx * ddx + ddy * ddy + ddz * ddz;
            }
        }
    }

    // Block reduction: wave shuffle -> cross-wave LDS -> per-block partial slot
    for (int off = 32; off > 0; off >>= 1) {
        lossAcc += __shfl_down(lossAcc, off);
        regAcc  += __shfl_down(regAcc, off);
    }
    const int wid = tid >> 6;
    if ((tid & 63) == 0) { redL[wid] = (double)lossAcc; redR[wid] = (double)regAcc; }
    __syncthreads();
    if (tid == 0) {
        double l = 0.0, r = 0.0;
        for (int i = 0; i < THREADS / 64; ++i) { l += redL[i]; r += redR[i]; }
        partials[2 * (size_t)blockIdx.x]     = l;
        partials[2 * (size_t)blockIdx.x + 1] = r;
    }
}

__global__ __launch_bounds__(256) void bbf_finalize(
    const float* __restrict__ lines,
    const double* __restrict__ partials,
    float* __restrict__ out_total)
{
    __shared__ double rl[4], rr[4];
    const int tid = threadIdx.x;
    double l = 0.0, r = 0.0;
    for (int i = tid; i < NBLK; i += 256) {
        l += partials[2 * (size_t)i];
        r += partials[2 * (size_t)i + 1];
    }
    for (int off = 32; off > 0; off >>= 1) {
        l += __shfl_down(l, off);
        r += __shfl_down(r, off);
    }
    const int wid = tid >> 6;
    if ((tid & 63) == 0) { rl[wid] = l; rr[wid] = r; }
    __syncthreads();
    if (tid == 0) {
        double L = 0.0, R = 0.0;
        for (int i = 0; i < 4; ++i) { L += rl[i]; R += rr[i]; }
        double reg1 = 0.0;
        for (int i = 0; i < NB; ++i) reg1 += (double)expf(lines[i]);
        const double loss = L / ((double)T_TOTAL * (double)NP);
        const double reg2 = R / ((double)(T_TOTAL - 1) * (double)NP);
        *out_total = (float)(loss + 0.001 * reg1 + 0.1 * reg2);
    }
}

extern "C" void kernel_launch(void* const* d_in, const int* in_sizes, int n_in,
                              void* d_out, int out_size, void* d_ws, size_t ws_size,
                              hipStream_t stream) {
    const float* lines  = (const float*)d_in[0];
    const float* rootsx = (const float*)d_in[1];
    const float* rootsy = (const float*)d_in[2];
    const float* rootsz = (const float*)d_in[3];
    const float* ax     = (const float*)d_in[4];
    const float* ay     = (const float*)d_in[5];
    const float* az     = (const float*)d_in[6];
    const float* tarx   = (const float*)d_in[7];
    const float* tary   = (const float*)d_in[8];
    const float* w      = (const float*)d_in[9];

    float* out = (float*)d_out;
    const size_t plane = (size_t)T_TOTAL * NP;
    float* outx = out;
    float* outy = out + plane;
    float* outz = out + 2 * plane;
    float* out_total = out + 3 * plane;

    double* partials = (double*)d_ws;   // 6250 * 2 doubles = 100 KB

    bbf_fused<<<NBLK, THREADS, 0, stream>>>(
        lines, rootsx, rootsy, rootsz, ax, ay, az, tarx, tary, w,
        outx, outy, outz, partials);
    bbf_finalize<<<1, 256, 0, stream>>>(lines, partials, out_total);
}

// Round 3
// 89.584 us; speedup vs baseline: 2.1364x; 1.1813x over previous
//
#include <hip/hip_runtime.h>

#define T_TOTAL 200000
#define NL 49
#define NP 50
#define NB 20
#define TB 32             // timesteps per block (200000 % 32 == 0)
#define THREADS 512
#define NBLK (T_TOTAL / TB)   // 6250

// 4 blocks/CU x 512 thr = 32 waves/CU (occupancy cap). Keep VGPR <= 64.
__global__ __launch_bounds__(THREADS, 8) void bbf_fused(
    const float* __restrict__ lines,
    const float* __restrict__ rootsx,
    const float* __restrict__ rootsy,
    const float* __restrict__ rootsz,
    const float* __restrict__ ax,
    const float* __restrict__ ay,
    const float* __restrict__ az,
    const float* __restrict__ tarx,
    const float* __restrict__ tary,
    const float* __restrict__ w,
    float* __restrict__ outx,
    float* __restrict__ outy,
    float* __restrict__ outz,
    double* __restrict__ partials)   // [NBLK][2]: loss, reg2 per block
{
    __shared__ __align__(16) float sdx[(TB + 1) * NL];
    __shared__ __align__(16) float sdy[(TB + 1) * NL];
    __shared__ __align__(16) float sdz[(TB + 1) * NL];
    // +4 pad: phase-4 reads two aligned float4s at j+48/j+52 (up to idx 1655)
    __shared__ __align__(16) float xs[(TB + 1) * NP + 8];
    __shared__ __align__(16) float ys[(TB + 1) * NP + 8];
    __shared__ __align__(16) float zs[(TB + 1) * NP + 8];
    __shared__ float Lexp[NL];
    __shared__ double redL[THREADS / 64], redR[THREADS / 64];

    const int tid = threadIdx.x;
    const int t0  = blockIdx.x * TB;
    const int nT  = min(TB + 1, T_TOTAL - t0);   // 33; last block 32
    const int nload = nT * NL;

    if (tid < NL) Lexp[tid] = expf(lines[tid % NB]);
    __syncthreads();

    // Phase 1+2: float4 global loads -> deltas -> float4 LDS writes (conflict-free)
    const float4* ax4 = (const float4*)(ax + (size_t)t0 * NL);
    const float4* ay4 = (const float4*)(ay + (size_t)t0 * NL);
    const float4* az4 = (const float4*)(az + (size_t)t0 * NL);
    const int nv4 = nload >> 2;
    for (int k4 = tid; k4 < nv4; k4 += THREADS) {
        const float4 X = ax4[k4];
        const float4 Y = ay4[k4];
        const float4 Z = az4[k4];
        const float fx[4] = {X.x, X.y, X.z, X.w};
        const float fy[4] = {Y.x, Y.y, Y.z, Y.w};
        const float fz[4] = {Z.x, Z.y, Z.z, Z.w};
        float ox[4], oy[4], oz[4];
        const int kb = k4 << 2;
#pragma unroll
        for (int c = 0; c < 4; ++c) {
            const int i = (kb + c) % NL;
            const float x = fx[c], y = fy[c], z = fz[c];
            const float nrm = sqrtf(x * x + y * y + z * z) + 1e-10f;
            const float s = Lexp[i] / nrm;
            ox[c] = x * s; oy[c] = y * s; oz[c] = z * s;
        }
        *(float4*)&sdx[kb] = make_float4(ox[0], ox[1], ox[2], ox[3]);
        *(float4*)&sdy[kb] = make_float4(oy[0], oy[1], oy[2], oy[3]);
        *(float4*)&sdz[kb] = make_float4(oz[0], oz[1], oz[2], oz[3]);
    }
    for (int k = (nv4 << 2) + tid; k < nload; k += THREADS) {   // scalar tail (<=1)
        const int i = k % NL;
        const float x = ax[(size_t)t0 * NL + k];
        const float y = ay[(size_t)t0 * NL + k];
        const float z = az[(size_t)t0 * NL + k];
        const float nrm = sqrtf(x * x + y * y + z * z) + 1e-10f;
        const float s = Lexp[i] / nrm;
        sdx[k] = x * s; sdy[k] = y * s; sdz[k] = z * s;
    }
    __syncthreads();

    // Phase 3: tree accumulation -> node positions in LDS (stride-1 scalar writes)
    const int npts = nT * NP;
    for (int j = tid; j < npts; j += THREADS) {
        const int t = j / NP;
        const int p = j - t * NP;
        float X = 0.f, Y = 0.f, Z = 0.f;
        int b = p;
        while (b > 0) {                     // <=5 iterations (tree depth)
            const int limb = b - 1;
            const int idx = t * NL + limb;
            X += sdx[idx];
            Y += sdy[idx];
            Z += sdz[idx];
            b = limb >> 1;                  // parent = (b-1)/2
        }
        const int tg = t0 + t;
        xs[j] = X + rootsx[tg];
        ys[j] = Y + rootsy[tg];
        zs[j] = Z + rootsz[tg];
    }
    __syncthreads();

    // Phase 4: float4 output writes + loss/reg2 partials
    const size_t gbase = (size_t)t0 * NP;
    const float4* tarx4 = (const float4*)(tarx + gbase);
    const float4* tary4 = (const float4*)(tary + gbase);
    const float4* w4    = (const float4*)(w + gbase);
    float4* outx4 = (float4*)(outx + gbase);
    float4* outy4 = (float4*)(outy + gbase);
    float4* outz4 = (float4*)(outz + gbase);

    float lossAcc = 0.f, regAcc = 0.f;
    for (int c = tid; c < (TB * NP) / 4; c += THREADS) {   // 400 float4s
        const int j = c << 2;
        const float4 X  = *(const float4*)&xs[j];
        const float4 Y  = *(const float4*)&ys[j];
        const float4 Z  = *(const float4*)&zs[j];
        outx4[c] = X;
        outy4[c] = Y;
        outz4[c] = Z;
        const float4 TX = tarx4[c];
        const float4 TY = tary4[c];
        const float4 WV = w4[c];
        // next-timestep values xs[j+50..j+53] via two aligned conflict-free b128 reads
        const float4 XA = *(const float4*)&xs[j + 48];
        const float4 XB = *(const float4*)&xs[j + 52];
        const float4 YA = *(const float4*)&ys[j + 48];
        const float4 YB = *(const float4*)&ys[j + 52];
        const float4 ZA = *(const float4*)&zs[j + 48];
        const float4 ZB = *(const float4*)&zs[j + 52];
        const float xv[4] = {X.x, X.y, X.z, X.w};
        const float yv[4] = {Y.x, Y.y, Y.z, Y.w};
        const float zv[4] = {Z.x, Z.y, Z.z, Z.w};
        const float tx[4] = {TX.x, TX.y, TX.z, TX.w};
        const float ty[4] = {TY.x, TY.y, TY.z, TY.w};
        const float wv[4] = {WV.x, WV.y, WV.z, WV.w};
        const float xn[4] = {XA.z, XA.w, XB.x, XB.y};
        const float yn[4] = {YA.z, YA.w, YB.x, YB.y};
        const float zn[4] = {ZA.z, ZA.w, ZB.x, ZB.y};
#pragma unroll
        for (int e = 0; e < 4; ++e) {
            const float dx = xv[e] - tx[e];
            const float dy = yv[e] - ty[e];
            lossAcc += wv[e] * (dx * dx + dy * dy);
            const int t = t0 + (j + e) / NP;
            if (t < T_TOTAL - 1) {
                const float ddx = xv[e] - xn[e];
                const float ddy = yv[e] - yn[e];
                const float ddz = zv[e] - zn[e];
                regAcc += ddx * ddx + ddy * ddy + ddz * ddz;
            }
        }
    }

    // Block reduction: wave shuffle -> cross-wave LDS -> per-block partial slot
    for (int off = 32; off > 0; off >>= 1) {
        lossAcc += __shfl_down(lossAcc, off);
        regAcc  += __shfl_down(regAcc, off);
    }
    const int wid = tid >> 6;
    if ((tid & 63) == 0) { redL[wid] = (double)lossAcc; redR[wid] = (double)regAcc; }
    __syncthreads();
    if (tid == 0) {
        double l = 0.0, r = 0.0;
        for (int i = 0; i < THREADS / 64; ++i) { l += redL[i]; r += redR[i]; }
        partials[2 * (size_t)blockIdx.x]     = l;
        partials[2 * (size_t)blockIdx.x + 1] = r;
    }
}

__global__ __launch_bounds__(256) void bbf_finalize(
    const float* __restrict__ lines,
    const double* __restrict__ partials,
    float* __restrict__ out_total)
{
    __shared__ double rl[4], rr[4];
    const int tid = threadIdx.x;
    double l = 0.0, r = 0.0;
    for (int i = tid; i < NBLK; i += 256) {
        l += partials[2 * (size_t)i];
        r += partials[2 * (size_t)i + 1];
    }
    for (int off = 32; off > 0; off >>= 1) {
        l += __shfl_down(l, off);
        r += __shfl_down(r, off);
    }
    const int wid = tid >> 6;
    if ((tid & 63) == 0) { rl[wid] = l; rr[wid] = r; }
    __syncthreads();
    if (tid == 0) {
        double L = 0.0, R = 0.0;
        for (int i = 0; i < 4; ++i) { L += rl[i]; R += rr[i]; }
        double reg1 = 0.0;
        for (int i = 0; i < NB; ++i) reg1 += (double)expf(lines[i]);
        const double loss = L / ((double)T_TOTAL * (double)NP);
        const double reg2 = R / ((double)(T_TOTAL - 1) * (double)NP);
        *out_total = (float)(loss + 0.001 * reg1 + 0.1 * reg2);
    }
}

extern "C" void kernel_launch(void* const* d_in, const int* in_sizes, int n_in,
                              void* d_out, int out_size, void* d_ws, size_t ws_size,
                              hipStream_t stream) {
    const float* lines  = (const float*)d_in[0];
    const float* rootsx = (const float*)d_in[1];
    const float* rootsy = (const float*)d_in[2];
    const float* rootsz = (const float*)d_in[3];
    const float* ax     = (const float*)d_in[4];
    const float* ay     = (const float*)d_in[5];
    const float* az     = (const float*)d_in[6];
    const float* tarx   = (const float*)d_in[7];
    const float* tary   = (const float*)d_in[8];
    const float* w      = (const float*)d_in[9];

    float* out = (float*)d_out;
    const size_t plane = (size_t)T_TOTAL * NP;
    float* outx = out;
    float* outy = out + plane;
    float* outz = out + 2 * plane;
    float* out_total = out + 3 * plane;

    double* partials = (double*)d_ws;   // 6250 * 2 doubles = 100 KB

    bbf_fused<<<NBLK, THREADS, 0, stream>>>(
        lines, rootsx, rootsy, rootsz, ax, ay, az, tarx, tary, w,
        outx, outy, outz, partials);
    bbf_finalize<<<1, 256, 0, stream>>>(lines, partials, out_total);
}

// Round 4
// 85.424 us; speedup vs baseline: 2.2405x; 1.0487x over previous
//
#include <hip/hip_runtime.h>

#define T_TOTAL 200000
#define NL 49
#define NP 50
#define NB 20
#define TB 32             // timesteps per block (200000 % 32 == 0)
#define THREADS 256
#define NBLK (T_TOTAL / TB)   // 6250

// LDS ~20.1 KB + 256 thr -> 8 blocks/CU = 32 waves/CU (occupancy cap).
// VGPR must stay <= 64 for 8 waves/EU.
__global__ __launch_bounds__(THREADS, 8) void bbf_fused(
    const float* __restrict__ lines,
    const float* __restrict__ rootsx,
    const float* __restrict__ rootsy,
    const float* __restrict__ rootsz,
    const float* __restrict__ ax,
    const float* __restrict__ ay,
    const float* __restrict__ az,
    const float* __restrict__ tarx,
    const float* __restrict__ tary,
    const float* __restrict__ w,
    float* __restrict__ outx,
    float* __restrict__ outy,
    float* __restrict__ outz,
    double* __restrict__ partials)   // [NBLK][2]: loss, reg2 per block
{
    __shared__ __align__(16) float sdx[(TB + 1) * NL];   // 6468 B
    __shared__ __align__(16) float sdy[(TB + 1) * NL];
    __shared__ __align__(16) float sdz[(TB + 1) * NL];
    __shared__ float rx[TB + 1], ry[TB + 1], rz[TB + 1];
    __shared__ float Lexp[NL];
    __shared__ double redL[THREADS / 64], redR[THREADS / 64];

    const int tid = threadIdx.x;
    const int t0  = blockIdx.x * TB;
    const int nT  = min(TB + 1, T_TOTAL - t0);   // 33; last block 32
    const int nload = nT * NL;

    // tiny staging: Lexp on wave 0, roots on wave 1 (issue in parallel)
    if (tid < NL) Lexp[tid] = expf(lines[tid % NB]);
    const int rtid = tid - 64;
    if (rtid >= 0 && rtid < nT) {
        rx[rtid] = rootsx[t0 + rtid];
        ry[rtid] = rootsy[t0 + rtid];
        rz[rtid] = rootsz[t0 + rtid];
    }
    __syncthreads();

    // Phase 1: float4 global loads -> deltas -> float4 LDS writes
    const float4* ax4 = (const float4*)(ax + (size_t)t0 * NL);
    const float4* ay4 = (const float4*)(ay + (size_t)t0 * NL);
    const float4* az4 = (const float4*)(az + (size_t)t0 * NL);
    const int nv4 = nload >> 2;                  // 404
    for (int k4 = tid; k4 < nv4; k4 += THREADS) {
        const float4 X = ax4[k4];
        const float4 Y = ay4[k4];
        const float4 Z = az4[k4];
        const float fx[4] = {X.x, X.y, X.z, X.w};
        const float fy[4] = {Y.x, Y.y, Y.z, Y.w};
        const float fz[4] = {Z.x, Z.y, Z.z, Z.w};
        float ox[4], oy[4], oz[4];
        const int kb = k4 << 2;
#pragma unroll
        for (int c = 0; c < 4; ++c) {
            const int i = (kb + c) % NL;
            const float x = fx[c], y = fy[c], z = fz[c];
            const float nrm = sqrtf(x * x + y * y + z * z) + 1e-10f;
            const float s = Lexp[i] / nrm;
            ox[c] = x * s; oy[c] = y * s; oz[c] = z * s;
        }
        *(float4*)&sdx[kb] = make_float4(ox[0], ox[1], ox[2], ox[3]);
        *(float4*)&sdy[kb] = make_float4(oy[0], oy[1], oy[2], oy[3]);
        *(float4*)&sdz[kb] = make_float4(oz[0], oz[1], oz[2], oz[3]);
    }
    for (int k = (nv4 << 2) + tid; k < nload; k += THREADS) {   // 1 tail element
        const int i = k % NL;
        const float x = ax[(size_t)t0 * NL + k];
        const float y = ay[(size_t)t0 * NL + k];
        const float z = az[(size_t)t0 * NL + k];
        const float nrm = sqrtf(x * x + y * y + z * z) + 1e-10f;
        const float s = Lexp[i] / nrm;
        sdx[k] = x * s; sdy[k] = y * s; sdz[k] = z * s;
    }
    __syncthreads();

    // Phase 2 (fused walk + loss + store): each element walks its own tree
    // path for (t,p) and (t+1,p); no position staging, no third barrier.
    const size_t gbase = (size_t)t0 * NP;
    const float4* tarx4 = (const float4*)(tarx + gbase);
    const float4* tary4 = (const float4*)(tary + gbase);
    const float4* w4    = (const float4*)(w + gbase);
    float4* outx4 = (float4*)(outx + gbase);
    float4* outy4 = (float4*)(outy + gbase);
    float4* outz4 = (float4*)(outz + gbase);

    float lossAcc = 0.f, regAcc = 0.f;
    for (int c = tid; c < (TB * NP) / 4; c += THREADS) {   // 400 float4 groups
        const int j = c << 2;
        int t = j / NP;
        int p = j - t * NP;
        const float4 TX = tarx4[c];
        const float4 TY = tary4[c];
        const float4 WV = w4[c];
        const float tx[4] = {TX.x, TX.y, TX.z, TX.w};
        const float ty[4] = {TY.x, TY.y, TY.z, TY.w};
        const float wv[4] = {WV.x, WV.y, WV.z, WV.w};
        float xo[4], yo[4], zo[4];
#pragma unroll
        for (int e = 0; e < 4; ++e) {
            float X = rx[t], Y = ry[t], Z = rz[t];
            int b = p;
            while (b > 0) {                    // <=5 steps (tree depth)
                const int limb = b - 1;
                const int idx = t * NL + limb;
                X += sdx[idx]; Y += sdy[idx]; Z += sdz[idx];
                b = limb >> 1;
            }
            xo[e] = X; yo[e] = Y; zo[e] = Z;
            const float dx = X - tx[e];
            const float dy = Y - ty[e];
            lossAcc += wv[e] * (dx * dx + dy * dy);
            if (t + 1 < nT) {                  // also covers global t+1 < T
                float X2 = rx[t + 1], Y2 = ry[t + 1], Z2 = rz[t + 1];
                int b2 = p;
                while (b2 > 0) {
                    const int limb = b2 - 1;
                    const int idx = (t + 1) * NL + limb;
                    X2 += sdx[idx]; Y2 += sdy[idx]; Z2 += sdz[idx];
                    b2 = limb >> 1;
                }
                const float ddx = X - X2;
                const float ddy = Y - Y2;
                const float ddz = Z - Z2;
                regAcc += ddx * ddx + ddy * ddy + ddz * ddz;
            }
            if (++p == NP) { p = 0; ++t; }
        }
        outx4[c] = make_float4(xo[0], xo[1], xo[2], xo[3]);
        outy4[c] = make_float4(yo[0], yo[1], yo[2], yo[3]);
        outz4[c] = make_float4(zo[0], zo[1], zo[2], zo[3]);
    }

    // Block reduction: wave shuffle -> cross-wave LDS -> per-block partial slot
    for (int off = 32; off > 0; off >>= 1) {
        lossAcc += __shfl_down(lossAcc, off);
        regAcc  += __shfl_down(regAcc, off);
    }
    const int wid = tid >> 6;
    if ((tid & 63) == 0) { redL[wid] = (double)lossAcc; redR[wid] = (double)regAcc; }
    __syncthreads();
    if (tid == 0) {
        double l = 0.0, r = 0.0;
        for (int i = 0; i < THREADS / 64; ++i) { l += redL[i]; r += redR[i]; }
        partials[2 * (size_t)blockIdx.x]     = l;
        partials[2 * (size_t)blockIdx.x + 1] = r;
    }
}

__global__ __launch_bounds__(256) void bbf_finalize(
    const float* __restrict__ lines,
    const double* __restrict__ partials,
    float* __restrict__ out_total)
{
    __shared__ double rl[4], rr[4];
    const int tid = threadIdx.x;
    double l = 0.0, r = 0.0;
    for (int i = tid; i < NBLK; i += 256) {
        l += partials[2 * (size_t)i];
        r += partials[2 * (size_t)i + 1];
    }
    for (int off = 32; off > 0; off >>= 1) {
        l += __shfl_down(l, off);
        r += __shfl_down(r, off);
    }
    const int wid = tid >> 6;
    if ((tid & 63) == 0) { rl[wid] = l; rr[wid] = r; }
    __syncthreads();
    if (tid == 0) {
        double L = 0.0, R = 0.0;
        for (int i = 0; i < 4; ++i) { L += rl[i]; R += rr[i]; }
        double reg1 = 0.0;
        for (int i = 0; i < NB; ++i) reg1 += (double)expf(lines[i]);
        const double loss = L / ((double)T_TOTAL * (double)NP);
        const double reg2 = R / ((double)(T_TOTAL - 1) * (double)NP);
        *out_total = (float)(loss + 0.001 * reg1 + 0.1 * reg2);
    }
}

extern "C" void kernel_launch(void* const* d_in, const int* in_sizes, int n_in,
                              void* d_out, int out_size, void* d_ws, size_t ws_size,
                              hipStream_t stream) {
    const float* lines  = (const float*)d_in[0];
    const float* rootsx = (const float*)d_in[1];
    const float* rootsy = (const float*)d_in[2];
    const float* rootsz = (const float*)d_in[3];
    const float* ax     = (const float*)d_in[4];
    const float* ay     = (const float*)d_in[5];
    const float* az     = (const float*)d_in[6];
    const float* tarx   = (const float*)d_in[7];
    const float* tary   = (const float*)d_in[8];
    const float* w      = (const float*)d_in[9];

    float* out = (float*)d_out;
    const size_t plane = (size_t)T_TOTAL * NP;
    float* outx = out;
    float* outy = out + plane;
    float* outz = out + 2 * plane;
    float* out_total = out + 3 * plane;

    double* partials = (double*)d_ws;   // 6250 * 2 doubles = 100 KB

    bbf_fused<<<NBLK, THREADS, 0, stream>>>(
        lines, rootsx, rootsy, rootsz, ax, ay, az, tarx, tary, w,
        outx, outy, outz, partials);
    bbf_finalize<<<1, 256, 0, stream>>>(lines, partials, out_total);
}